// Round 2
// baseline (410.890 us; speedup 1.0000x reference)
//
#include <hip/hip_runtime.h>
#include <math.h>

// B=1e6, S=5, I=8. One thread per batch element. Memory-bound streaming:
// ~236 MB read + ~224 MB write -> ~73 us floor at 6.3 TB/s.
// Inputs (dict order): x(B,5), W1d(B,3,8), W1m(B,3,8), s1d(B,3), s1m(B,3),
//   excitatory_rule(3,8) f32, learning_rate(3,8) f32,
//   driving_rule(3,8) i32, learning_rule(3,8) i32
// Output (concat flat): output(B,2), W1d_new(B,24), W1m_new(B,24), out1(B,3), out2(B,3)

__device__ __forceinline__ float upd_elem(float W, float xb, float yb,
                                          float lr, int rule, float exc) {
    float w = fabsf(W);
    float delta;
    if (rule == 0) {
        delta = lr * xb * yb * (1.f - w);
    } else if (rule == 1) {
        delta = lr * (w * (xb - 1.f) * yb + (1.f - w) * xb * yb);
    } else if (rule == 2) {
        delta = lr * (w * xb * (yb - 1.f) + (1.f - w) * xb * yb);
    } else {
        float d = tanhf(4.f * (1.f - fabsf(xb - yb) - 2.f));
        delta = lr * ((d > 0.f) ? d * (1.f - w) : d * w);
    }
    float wn = w + delta;
    // where(exc*wn < 0, wn*exc, wn)
    return (exc * wn < 0.f) ? wn * exc : wn;
}

__global__ __launch_bounds__(256) void nn_plastic_kernel(
    const float* __restrict__ x,       // (B,5)
    const float* __restrict__ W1d,     // (B,3,8)
    const float* __restrict__ W1m,     // (B,3,8)
    const float* __restrict__ s1d,     // (B,3)
    const float* __restrict__ s1m,     // (B,3)
    const float* __restrict__ exc_t,   // (3,8)
    const float* __restrict__ lr_t,    // (3,8)
    const int*   __restrict__ drive_t, // (3,8)
    const int*   __restrict__ rule_t,  // (3,8)
    float* __restrict__ out,
    int B)
{
    int b = blockIdx.x * blockDim.x + threadIdx.x;
    if (b >= B) return;

    // ---- load x1 = [x, s1d], x2 = [x, s1m] ----
    float x1[8], x2[8];
#pragma unroll
    for (int j = 0; j < 5; ++j) {
        float v = x[b * 5 + j];
        x1[j] = v; x2[j] = v;
    }
#pragma unroll
    for (int j = 0; j < 3; ++j) {
        x1[5 + j] = s1d[b * 3 + j];
        x2[5 + j] = s1m[b * 3 + j];
    }

    // ---- load W1d, W1m (24 f32 each, 16B-aligned per-b base) ----
    float4 wd[6], wm[6];
    const float4* W1d4 = reinterpret_cast<const float4*>(W1d) + (size_t)b * 6;
    const float4* W1m4 = reinterpret_cast<const float4*>(W1m) + (size_t)b * 6;
#pragma unroll
    for (int k = 0; k < 6; ++k) { wd[k] = W1d4[k]; wm[k] = W1m4[k]; }
    float* wdf = reinterpret_cast<float*>(wd);
    float* wmf = reinterpret_cast<float*>(wm);

    // ---- forward: out1 = sigmoid(W1d @ x1); out2 = 0.5*sigmoid(W1m @ x2)+0.5 ----
    float out1[3], out2[3];
#pragma unroll
    for (int i = 0; i < 3; ++i) {
        float a1 = 0.f, a2 = 0.f;
#pragma unroll
        for (int j = 0; j < 8; ++j) {
            a1 = fmaf(wdf[i * 8 + j], x1[j], a1);
            a2 = fmaf(wmf[i * 8 + j], x2[j], a2);
        }
        out1[i] = 1.f / (1.f + expf(-a1));
        out2[i] = 0.5f / (1.f + expf(-a2)) + 0.5f;
    }

    // ---- plastic updates, IN PLACE (each W element read exactly once here;
    //      drive picks which matrix updates per (i,j)) ----
#pragma unroll
    for (int i = 0; i < 3; ++i) {
#pragma unroll
        for (int j = 0; j < 8; ++j) {
            const int k = i * 8 + j;
            // uniform (thread-independent) addresses -> s_load, uniform branches
            const float lr  = lr_t[k];
            const float exc = exc_t[k];
            const int   rul = rule_t[k];
            const int   drv = drive_t[k];
            if (drv == 1) {
                wdf[k] = upd_elem(wdf[k], x1[j], out1[i], lr, rul, exc);
            } else {
                wmf[k] = upd_elem(wmf[k], x2[j], out2[i], lr, rul, exc);
            }
        }
    }

    // ---- stores ----
    float* out_o  = out;                    // (B,2)
    float* out_wd = out + (size_t)B * 2;    // (B,24), byte off 8e6   (16B aligned)
    float* out_wm = out + (size_t)B * 26;   // (B,24), byte off 104e6 (16B aligned)
    float* out_o1 = out + (size_t)B * 50;   // (B,3)
    float* out_o2 = out + (size_t)B * 53;   // (B,3)

    float4* wd_out4 = reinterpret_cast<float4*>(out_wd) + (size_t)b * 6;
    float4* wm_out4 = reinterpret_cast<float4*>(out_wm) + (size_t)b * 6;
#pragma unroll
    for (int k = 0; k < 6; ++k) { wd_out4[k] = wd[k]; wm_out4[k] = wm[k]; }

    float2 o = make_float2(out1[1] * out1[1], out1[2] * out1[2]);
    reinterpret_cast<float2*>(out_o)[b] = o;
#pragma unroll
    for (int i = 0; i < 3; ++i) {
        out_o1[b * 3 + i] = out1[i];
        out_o2[b * 3 + i] = out2[i];
    }
}

extern "C" void kernel_launch(void* const* d_in, const int* in_sizes, int n_in,
                              void* d_out, int out_size, void* d_ws, size_t ws_size,
                              hipStream_t stream) {
    const float* x    = (const float*)d_in[0];
    const float* W1d  = (const float*)d_in[1];
    const float* W1m  = (const float*)d_in[2];
    const float* s1d  = (const float*)d_in[3];
    const float* s1m  = (const float*)d_in[4];
    const float* exc  = (const float*)d_in[5];
    const float* lr   = (const float*)d_in[6];
    const int*   drv  = (const int*)d_in[7];
    const int*   rul  = (const int*)d_in[8];
    float* out = (float*)d_out;

    const int B = in_sizes[0] / 5;  // x is (B,5)
    const int block = 256;
    const int grid = (B + block - 1) / block;
    nn_plastic_kernel<<<grid, block, 0, stream>>>(
        x, W1d, W1m, s1d, s1m, exc, lr, drv, rul, out, B);
}

// Round 6
// 400.366 us; speedup vs baseline: 1.0263x; 1.0263x over previous
//
#include <hip/hip_runtime.h>
#include <math.h>

// B=1e6, S=5, I=8. One thread per batch element.
// Memory-bound streaming: ~236 MB read + ~224 MB write -> ~73 us floor @ 6.3 TB/s.
// Round-2 rocprof: 141 us @ 2.55 TB/s, VALUBusy 12.8%, VGPR 44 -> latency/request
// bound (serialized scattered loads, ~2-3 lines outstanding/wave).
// Fix: stage W1d/W1m tiles through LDS with async global_load_lds (coalesced,
// no VGPR cost, 12 loads in flight), per-thread private slice update in place,
// coalesced float4 store-back. 48 KB LDS -> 3 blocks/CU (12 waves/CU).
//
// Inputs (dict order): x(B,5), W1d(B,3,8), W1m(B,3,8), s1d(B,3), s1m(B,3),
//   excitatory_rule(3,8) f32, learning_rate(3,8) f32,
//   driving_rule(3,8) i32, learning_rule(3,8) i32
// Output (concat flat): output(B,2), W1d_new(B,24), W1m_new(B,24), out1(B,3), out2(B,3)

__device__ __forceinline__ void gload_lds16(const float* g, float* lds) {
    __builtin_amdgcn_global_load_lds(
        (const __attribute__((address_space(1))) void*)g,
        (__attribute__((address_space(3))) void*)lds,
        16, 0, 0);
}

__device__ __forceinline__ float upd_elem(float W, float xb, float yb,
                                          float lr, int rule, float exc) {
    float w = fabsf(W);
    float delta;
    if (rule == 0) {
        delta = lr * xb * yb * (1.f - w);
    } else if (rule == 1) {
        delta = lr * (w * (xb - 1.f) * yb + (1.f - w) * xb * yb);
    } else if (rule == 2) {
        delta = lr * (w * xb * (yb - 1.f) + (1.f - w) * xb * yb);
    } else {
        float d = tanhf(4.f * (1.f - fabsf(xb - yb) - 2.f));
        delta = lr * ((d > 0.f) ? d * (1.f - w) : d * w);
    }
    float wn = w + delta;
    return (exc * wn < 0.f) ? wn * exc : wn;  // where(exc*wn<0, wn*exc, wn)
}

__global__ __launch_bounds__(256, 3) void nn_plastic_kernel(
    const float* __restrict__ x,       // (B,5)
    const float* __restrict__ W1d,     // (B,3,8)
    const float* __restrict__ W1m,     // (B,3,8)
    const float* __restrict__ s1d,     // (B,3)
    const float* __restrict__ s1m,     // (B,3)
    const float* __restrict__ exc_t,   // (3,8)
    const float* __restrict__ lr_t,    // (3,8)
    const int*   __restrict__ drive_t, // (3,8)
    const int*   __restrict__ rule_t,  // (3,8)
    float* __restrict__ out,
    int B)
{
    __shared__ float wA[6144];  // 24 KB: this block's W1d tile (256 x 24 f32, linear)
    __shared__ float wB[6144];  // 24 KB: this block's W1m tile

    const int t = threadIdx.x;
    const long long b      = (long long)blockIdx.x * 256 + t;
    const long long total4 = (long long)B * 6;          // total float4s per W array
    const long long base4  = (long long)blockIdx.x * 1536;
    const bool act = (b < (long long)B);

    // ---- async coalesced staging of both W tiles (no VGPR round-trip) ----
    // Block slot s = k*256+t covers float4 #(base4+s); LDS dest is linear in
    // lane order (wave base + lane*16) as global_load_lds requires. Boundary
    // guard falls on wave boundaries (valid tail = 384 = 6*64 float4s).
    const float4* W1d4 = (const float4*)W1d;
    const float4* W1m4 = (const float4*)W1m;
#pragma unroll
    for (int k = 0; k < 6; ++k) {
        long long idx = base4 + k * 256 + t;
        if (idx < total4) {
            gload_lds16((const float*)(W1d4 + idx), &wA[(k * 256 + t) * 4]);
            gload_lds16((const float*)(W1m4 + idx), &wB[(k * 256 + t) * 4]);
        }
    }

    // ---- scalar x/s loads overlap the staging ----
    float xv[5], sdv[3], smv[3];
    if (act) {
#pragma unroll
        for (int j = 0; j < 5; ++j) xv[j] = x[b * 5 + j];
#pragma unroll
        for (int j = 0; j < 3; ++j) { sdv[j] = s1d[b * 3 + j]; smv[j] = s1m[b * 3 + j]; }
    }

    __syncthreads();  // staging complete (vmcnt+lgkmcnt drained by barrier)

    float out1[3], out2[3];
    if (act) {
        // ---- phase 1: W1d (private 96B LDS slice; no cross-thread hazard) ----
        float4 wd[6];
#pragma unroll
        for (int c = 0; c < 6; ++c) wd[c] = *(const float4*)&wA[t * 24 + c * 4];
        float* wdf = (float*)wd;
#pragma unroll
        for (int i = 0; i < 3; ++i) {
            float a = 0.f;
#pragma unroll
            for (int j = 0; j < 5; ++j) a = fmaf(wdf[i * 8 + j], xv[j], a);
#pragma unroll
            for (int j = 0; j < 3; ++j) a = fmaf(wdf[i * 8 + 5 + j], sdv[j], a);
            out1[i] = 1.f / (1.f + expf(-a));
        }
#pragma unroll
        for (int i = 0; i < 3; ++i) {
#pragma unroll
            for (int j = 0; j < 8; ++j) {
                const int k = i * 8 + j;
                if (drive_t[k] == 1) {  // uniform branch, table reads stay scalar
                    float xb = (j < 5) ? xv[j] : sdv[j - 5];
                    wdf[k] = upd_elem(wdf[k], xb, out1[i], lr_t[k], rule_t[k], exc_t[k]);
                }
            }
        }
#pragma unroll
        for (int c = 0; c < 6; ++c) *(float4*)&wA[t * 24 + c * 4] = wd[c];

        // ---- phase 2: W1m ----
        float4 wm[6];
#pragma unroll
        for (int c = 0; c < 6; ++c) wm[c] = *(const float4*)&wB[t * 24 + c * 4];
        float* wmf = (float*)wm;
#pragma unroll
        for (int i = 0; i < 3; ++i) {
            float a = 0.f;
#pragma unroll
            for (int j = 0; j < 5; ++j) a = fmaf(wmf[i * 8 + j], xv[j], a);
#pragma unroll
            for (int j = 0; j < 3; ++j) a = fmaf(wmf[i * 8 + 5 + j], smv[j], a);
            out2[i] = 0.5f / (1.f + expf(-a)) + 0.5f;
        }
#pragma unroll
        for (int i = 0; i < 3; ++i) {
#pragma unroll
            for (int j = 0; j < 8; ++j) {
                const int k = i * 8 + j;
                if (drive_t[k] != 1) {
                    float xb = (j < 5) ? xv[j] : smv[j - 5];
                    wmf[k] = upd_elem(wmf[k], xb, out2[i], lr_t[k], rule_t[k], exc_t[k]);
                }
            }
        }
#pragma unroll
        for (int c = 0; c < 6; ++c) *(float4*)&wB[t * 24 + c * 4] = wm[c];
    }

    __syncthreads();  // all writebacks visible for the coalesced store

    // ---- coalesced float4 store-back of both updated tiles ----
    float* out_wd = out + (size_t)B * 2;    // (B,24), 16B-aligned offset
    float* out_wm = out + (size_t)B * 26;   // (B,24), 16B-aligned offset
    float4* out_wd4 = (float4*)out_wd;
    float4* out_wm4 = (float4*)out_wm;
#pragma unroll
    for (int k = 0; k < 6; ++k) {
        long long idx = base4 + k * 256 + t;
        if (idx < total4) {
            out_wd4[idx] = *(const float4*)&wA[(k * 256 + t) * 4];
            out_wm4[idx] = *(const float4*)&wB[(k * 256 + t) * 4];
        }
    }

    // ---- small outputs ----
    if (act) {
        float* out_o1 = out + (size_t)B * 50;   // (B,3)
        float* out_o2 = out + (size_t)B * 53;   // (B,3)
        ((float2*)out)[b] = make_float2(out1[1] * out1[1], out1[2] * out1[2]);
#pragma unroll
        for (int i = 0; i < 3; ++i) {
            out_o1[b * 3 + i] = out1[i];
            out_o2[b * 3 + i] = out2[i];
        }
    }
}

extern "C" void kernel_launch(void* const* d_in, const int* in_sizes, int n_in,
                              void* d_out, int out_size, void* d_ws, size_t ws_size,
                              hipStream_t stream) {
    const float* x    = (const float*)d_in[0];
    const float* W1d  = (const float*)d_in[1];
    const float* W1m  = (const float*)d_in[2];
    const float* s1d  = (const float*)d_in[3];
    const float* s1m  = (const float*)d_in[4];
    const float* exc  = (const float*)d_in[5];
    const float* lr   = (const float*)d_in[6];
    const int*   drv  = (const int*)d_in[7];
    const int*   rul  = (const int*)d_in[8];
    float* out = (float*)d_out;

    const int B = in_sizes[0] / 5;  // x is (B,5)
    const int block = 256;
    const int grid = (B + block - 1) / block;
    nn_plastic_kernel<<<grid, block, 0, stream>>>(
        x, W1d, W1m, s1d, s1m, exc, lr, drv, rul, out, B);
}